// Round 10
// baseline (276.134 us; speedup 1.0000x reference)
//
#include <hip/hip_runtime.h>
#include <hip/hip_fp16.h>
#include <math.h>

#define HIDK 4096
#define NHQ 32
#define HD 128
#define CMAX 4608
#define CLEN 4096
#define NCH 32          // 128-position chunks
#define SCALE 0.08838834764831845f   // 1/sqrt(128)

__device__ __forceinline__ float4 ld4(const float* p) { return *reinterpret_cast<const float4*>(p); }
__device__ __forceinline__ float dot4(float4 a, float4 b) { return a.x*b.x + a.y*b.y + a.z*b.z + a.w*b.w; }

// ---------------------------------------------------------------------------
// GEMM (gemm3, proven): out[bs,o] = sum_k X[bs,k]*W[o,k], 4 waves/block,
// 2 outputs/wave, X double-buffered through LDS.
// ---------------------------------------------------------------------------
__global__ __launch_bounds__(256) void gemm3_kernel(
    const float* __restrict__ X,
    const float* __restrict__ W1, const float* __restrict__ W2, const float* __restrict__ W3,
    int n1, int n2,
    float* __restrict__ o1, int os1,
    float* __restrict__ o2, int os2,
    float* __restrict__ o3, int os3)
{
  __shared__ float Xs[2][16][256];

  const int tid = threadIdx.x, lane = tid & 63, w = tid >> 6;
  const int o = blockIdx.x * 8 + w * 2;

  const float* Wb; float* ob; int os;
  if (o < n1)           { Wb = W1 + (size_t)o * HIDK;            ob = o1 + o;            os = os1; }
  else if (o < n1 + n2) { const int f = o - n1;      Wb = W2 + (size_t)f * HIDK; ob = o2 + f; os = os2; }
  else                  { const int f = o - n1 - n2; Wb = W3 + (size_t)f * HIDK; ob = o3 + f; os = os3; }

  const int strow = tid >> 6;
  const int stcol = (tid & 63) * 4;

  float acc0[16], acc1[16];
  #pragma unroll
  for (int b = 0; b < 16; ++b) { acc0[b] = 0.f; acc1[b] = 0.f; }

  #pragma unroll
  for (int j = 0; j < 4; ++j)
    *(float4*)&Xs[0][strow + j * 4][stcol] = ld4(X + (size_t)(strow + j * 4) * HIDK + stcol);

  int cur = 0;
  #pragma unroll 2
  for (int kt = 0; kt < 16; ++kt) {
    const float4 w0 = ld4(Wb + (size_t)kt * 256 + lane * 4);
    const float4 w1 = ld4(Wb + HIDK + (size_t)kt * 256 + lane * 4);
    float4 g[4];
    if (kt < 15) {
      #pragma unroll
      for (int j = 0; j < 4; ++j)
        g[j] = ld4(X + (size_t)(strow + j * 4) * HIDK + (kt + 1) * 256 + stcol);
    }
    __syncthreads();
    #pragma unroll
    for (int b = 0; b < 16; ++b) {
      const float4 x4 = *(const float4*)&Xs[cur][b][lane * 4];
      acc0[b] += dot4(x4, w0);
      acc1[b] += dot4(x4, w1);
    }
    if (kt < 15) {
      #pragma unroll
      for (int j = 0; j < 4; ++j)
        *(float4*)&Xs[cur ^ 1][strow + j * 4][stcol] = g[j];
    }
    cur ^= 1;
  }

  #pragma unroll
  for (int m = 1; m < 64; m <<= 1)
    #pragma unroll
    for (int b = 0; b < 16; ++b) {
      acc0[b] += __shfl_xor(acc0[b], m, 64);
      acc1[b] += __shfl_xor(acc1[b], m, 64);
    }
  if (lane == 0) {
    #pragma unroll
    for (int b = 0; b < 16; ++b) {
      ob[(size_t)b * os]     = acc0[b];
      ob[(size_t)b * os + 1] = acc1[b];
    }
  }
}

// ---------------------------------------------------------------------------
// Q prep: RoPE * SCALE -> qt[bkv][r][d]  (r = hl*4+s, d = 0..127)
// ---------------------------------------------------------------------------
__global__ __launch_bounds__(256) void qt_prep_kernel(
    const float* __restrict__ qraw, const float* __restrict__ cosp,
    const float* __restrict__ sinp, float* __restrict__ qt)
{
  const int e = blockIdx.x * 256 + threadIdx.x;   // 65536 total
  const int d = e & 127;
  const int r = (e >> 7) & 15;     // hl*4 + s
  const int bkv = e >> 11;         // 0..31
  const int b = bkv >> 3, kv = bkv & 7;
  const int s = r & 3, hl = r >> 2;
  const float* qp = qraw + (size_t)(b * 4 + s) * HIDK + (kv * 4 + hl) * HD;
  const float c  = cosp[(b * 4 + s) * HD + d];
  const float sn = sinp[(b * 4 + s) * HD + d];
  const float sgn = (d < 64) ? -1.f : 1.f;
  qt[e] = (qp[d] * c + sgn * qp[d ^ 64] * sn) * SCALE;
}

// ---------------------------------------------------------------------------
// Attention attn7: 1024 blocks x 256 thr (4 waves), 16 waves/CU.
// Block = (bkv, 128-pos chunk). Phase1: wave (ph,dh) partial scores for
// pos=ph*64+lane, dims dh*64..+63 -> Pex. Phase2: wave (ph,rh) softmax for
// rows rh*8..+8 with common max via Mex/Lex. Phase3: wave w = d-quarter over
// all 128 pos. No redundant HBM traffic; 3 barriers; ring prefetch.
// ---------------------------------------------------------------------------
__global__ __launch_bounds__(256, 4) void attn7_kernel(
    const float* __restrict__ qt, const float* __restrict__ Kc, const float* __restrict__ Vc,
    __half* __restrict__ partOh, float* __restrict__ partM, float* __restrict__ partL)
{
  __shared__ float Pex[2][128][21];   // 21.0 KB partial scores [dh][pos][row]
  __shared__ float P[128][21];        // 10.5 KB probabilities [pos][row]
  __shared__ float Mex[2][16];        // per-pos-half row maxima
  __shared__ float Lex[2][16];        // per-pos-half row sums

  const int tid = threadIdx.x, lane = tid & 63, w = tid >> 6;
  const int ph = w >> 1, sub = w & 1;        // sub = dh (phase1) / rh (phase2)
  const int chunk = blockIdx.x & 31, bkv = blockIdx.x >> 5;
  const int b = bkv >> 3, kv = bkv & 7;
  const int p0 = chunk * 128;

  const float* Kb = Kc + ((size_t)bkv * CMAX + p0) * HD;
  const float* Vb = Vc + ((size_t)bkv * CMAX + p0) * HD;
  const float* qb = qt + (size_t)bkv * 2048;   // [r][128]

  const int pos = ph * 64 + lane;

  // ---- phase 1: partial scores (64 dims each), ring-prefetched K ----
  {
    const float* Kp = Kb + (size_t)pos * HD + sub * 64;
    float ps[16];
    #pragma unroll
    for (int r = 0; r < 16; ++r) ps[r] = 0.f;

    float4 kb4[4];
    #pragma unroll
    for (int j = 0; j < 4; ++j) kb4[j] = ld4(Kp + j * 4);

    #pragma unroll
    for (int i = 0; i < 16; ++i) {
      const float4 k4 = kb4[i & 3];
      if (i < 12) kb4[i & 3] = ld4(Kp + (i + 4) * 4);
      #pragma unroll
      for (int r = 0; r < 16; ++r) {
        const float4 q4 = ld4(qb + r * 128 + sub * 64 + i * 4);
        ps[r] += dot4(k4, q4);
      }
    }
    #pragma unroll
    for (int r = 0; r < 16; ++r) Pex[sub][pos][r] = ps[r];
  }
  __syncthreads();

  // ---- phase 2a: row max over this pos-half (rows sub*8..+8) ----
  float sc[8], mreg[8];
  #pragma unroll
  for (int r = 0; r < 8; ++r) {
    const int row = sub * 8 + r;
    sc[r] = Pex[0][pos][row] + Pex[1][pos][row];
    float mx = sc[r];
    #pragma unroll
    for (int st = 1; st < 64; st <<= 1) mx = fmaxf(mx, __shfl_xor(mx, st, 64));
    mreg[r] = mx;
  }
  if (lane == 0) {
    #pragma unroll
    for (int r = 0; r < 8; ++r) Mex[ph][sub * 8 + r] = mreg[r];
  }
  __syncthreads();

  // ---- phase 2b: probabilities with common max, partial sums ----
  {
    float lreg[8];
    #pragma unroll
    for (int r = 0; r < 8; ++r) {
      const int row = sub * 8 + r;
      const float mc = fmaxf(Mex[0][row], Mex[1][row]);
      const float p = __expf(sc[r] - mc);
      float ls = p;
      #pragma unroll
      for (int st = 1; st < 64; st <<= 1) ls += __shfl_xor(ls, st, 64);
      lreg[r] = ls;
      P[pos][row] = p;
    }
    if (lane == 0) {
      #pragma unroll
      for (int r = 0; r < 8; ++r) Lex[ph][sub * 8 + r] = lreg[r];
    }
  }
  __syncthreads();

  // ---- phase 3: partM/partL writes (waves 0,1) + PV over d-quarter w ----
  if (ph == 0 && lane < 8) {
    const int row = sub * 8 + lane;
    const int hl = row >> 2, s = row & 3;
    const int grow = (b * NHQ + kv * 4 + hl) * 4 + s;
    partM[grow * NCH + chunk] = fmaxf(Mex[0][row], Mex[1][row]);
    partL[grow * NCH + chunk] = Lex[0][row] + Lex[1][row];
  }

  const int dc = lane & 7, pp = lane >> 3;
  const float* Vp = Vb + (size_t)pp * HD + w * 32 + dc * 4;

  float4 o[16];
  #pragma unroll
  for (int r = 0; r < 16; ++r) o[r] = make_float4(0.f, 0.f, 0.f, 0.f);

  float4 vb4[4];
  #pragma unroll
  for (int j = 0; j < 4; ++j) vb4[j] = ld4(Vp + (size_t)(8 * j) * HD);

  #pragma unroll
  for (int i = 0; i < 16; ++i) {
    const float4 v4 = vb4[i & 3];
    if (i < 12) vb4[i & 3] = ld4(Vp + (size_t)(8 * (i + 4)) * HD);
    const int pv = 8 * i + pp;
    #pragma unroll
    for (int r = 0; r < 16; ++r) {
      const float p = P[pv][r];
      o[r].x += p * v4.x; o[r].y += p * v4.y; o[r].z += p * v4.z; o[r].w += p * v4.w;
    }
  }

  // reduce over the 8 pos-phases (lanes differing in bits 3..5)
  #pragma unroll
  for (int r = 0; r < 16; ++r) {
    #pragma unroll
    for (int st = 8; st < 64; st <<= 1) {
      o[r].x += __shfl_xor(o[r].x, st, 64);
      o[r].y += __shfl_xor(o[r].y, st, 64);
      o[r].z += __shfl_xor(o[r].z, st, 64);
      o[r].w += __shfl_xor(o[r].w, st, 64);
    }
  }
  if (pp == 0) {
    #pragma unroll
    for (int r = 0; r < 16; ++r) {
      const int hl = r >> 2, s = r & 3;
      const int grow = (b * NHQ + kv * 4 + hl) * 4 + s;
      const size_t idx = ((size_t)grow * NCH + chunk) * HD + w * 32 + dc * 4;
      *(__half2*)&partOh[idx]     = __floats2half2_rn(o[r].x, o[r].y);
      *(__half2*)&partOh[idx + 2] = __floats2half2_rn(o[r].z, o[r].w);
    }
  }
}

// ---------------------------------------------------------------------------
// Flash-combine 32 chunk partials (fp16) + <=4 new causal tokens. 512 x 64.
// ---------------------------------------------------------------------------
__global__ __launch_bounds__(64) void combine_kernel(
    const float* __restrict__ qt, const float* __restrict__ kraw, const float* __restrict__ vraw,
    const float* __restrict__ cosp, const float* __restrict__ sinp,
    const __half* __restrict__ partOh, const float* __restrict__ partM, const float* __restrict__ partL,
    float* __restrict__ attn)
{
  const int bid = blockIdx.x;             // ((b*32 + h)*4 + s)
  const int s = bid & 3;
  const int h = (bid >> 2) & 31;
  const int b = bid >> 7;
  const int kv = h >> 2;
  const int lane = threadIdx.x;
  const int d0 = lane * 2;

  float M = -INFINITY;
  #pragma unroll 4
  for (int c = 0; c < NCH; ++c) M = fmaxf(M, partM[bid * NCH + c]);

  const int rloc = (h & 3) * 4 + s;
  const float qr0 = qt[((size_t)(b * 8 + kv) * 16 + rloc) * 128 + d0];
  const float qr1 = qt[((size_t)(b * 8 + kv) * 16 + rloc) * 128 + d0 + 1];

  float sj[4] = {0.f, 0.f, 0.f, 0.f};
  float Mp = M;
  #pragma unroll
  for (int j = 0; j < 4; ++j) {
    if (j <= s) {
      const float* kp = kraw + (size_t)(b * 4 + j) * 1024 + kv * HD;
      const float c0 = cosp[(b * 4 + j) * HD + d0],     sn0 = sinp[(b * 4 + j) * HD + d0];
      const float c1 = cosp[(b * 4 + j) * HD + d0 + 1], sn1 = sinp[(b * 4 + j) * HD + d0 + 1];
      const float sg0 = (d0 < 64) ? -1.f : 1.f;
      const float sg1 = ((d0 + 1) < 64) ? -1.f : 1.f;
      const float kr0 = kp[d0] * c0 + sg0 * kp[d0 ^ 64] * sn0;
      const float kr1 = kp[d0 + 1] * c1 + sg1 * kp[(d0 + 1) ^ 64] * sn1;
      float part = qr0 * kr0 + qr1 * kr1;
      #pragma unroll
      for (int m = 1; m < 64; m <<= 1) part += __shfl_xor(part, m, 64);
      sj[j] = part;
      Mp = fmaxf(Mp, part);
    }
  }

  float ltot = 0.f, O0 = 0.f, O1 = 0.f;
  #pragma unroll 4
  for (int c = 0; c < NCH; ++c) {
    const float a = __expf(partM[bid * NCH + c] - Mp);
    ltot += partL[bid * NCH + c] * a;
    const float2 v = __half22float2(*(const __half2*)&partOh[((size_t)bid * NCH + c) * HD + d0]);
    O0 += a * v.x;
    O1 += a * v.y;
  }
  #pragma unroll
  for (int j = 0; j < 4; ++j) {
    if (j <= s) {
      const float e = __expf(sj[j] - Mp);
      ltot += e;
      const float* vp = vraw + (size_t)(b * 4 + j) * 1024 + kv * HD + d0;
      O0 += e * vp[0];
      O1 += e * vp[1];
    }
  }
  const float inv = 1.f / ltot;
  *(float2*)&attn[(size_t)(b * 4 + s) * HIDK + h * HD + d0] = make_float2(O0 * inv, O1 * inv);
}

// ---------------------------------------------------------------------------
extern "C" void kernel_launch(void* const* d_in, const int* in_sizes, int n_in,
                              void* d_out, int out_size, void* d_ws, size_t ws_size,
                              hipStream_t stream)
{
  const float* hid  = (const float*)d_in[0];
  const float* cosp = (const float*)d_in[1];
  const float* sinp = (const float*)d_in[2];
  const float* Kc   = (const float*)d_in[3];
  const float* Vc   = (const float*)d_in[4];
  const float* Wq   = (const float*)d_in[5];
  const float* Wk   = (const float*)d_in[6];
  const float* Wv   = (const float*)d_in[7];
  const float* Wo   = (const float*)d_in[8];
  float* out = (float*)d_out;

  float* ws    = (float*)d_ws;
  float*  kraw   = ws;                      // 16384
  float*  vraw   = ws + 16384;              // 16384
  float*  attn   = ws + 32768;              // 65536
  float*  qt     = ws + 98304;              // 65536
  float*  qraw   = ws + 163840;             // 65536
  float*  partM  = ws + 229376;             // 512*32 = 16384
  float*  partL  = ws + 245760;             // 16384
  __half* partOh = (__half*)(ws + 262144);  // 512*32*128 halves = 1048576 float-slots
  // total 1,310,720 floats = 5.24 MB

  // A: QKV projection (raw, un-roped)
  gemm3_kernel<<<768, 256, 0, stream>>>(hid, Wq, Wk, Wv, 4096, 1024,
                                        qraw, 4096, kraw, 1024, vraw, 1024);
  // A': RoPE + scale q -> qt[bkv][r][d]
  qt_prep_kernel<<<256, 256, 0, stream>>>(qraw, cosp, sinp, qt);
  // B: attention over the 4096 cached positions
  attn7_kernel<<<1024, 256, 0, stream>>>(qt, Kc, Vc, partOh, partM, partL);
  // C: combine + new causal tokens
  combine_kernel<<<512, 64, 0, stream>>>(qt, kraw, vraw, cosp, sinp,
                                         partOh, partM, partL, attn);
  // D: output projection
  gemm3_kernel<<<512, 256, 0, stream>>>(attn, Wo, Wo, Wo, 4096, 0,
                                        out, 4096, out, 4096, out, 4096);
}

// Round 12
// 159.905 us; speedup vs baseline: 1.7269x; 1.7269x over previous
//
#include <hip/hip_runtime.h>
#include <hip/hip_fp16.h>
#include <math.h>

#define HIDK 4096
#define NHQ 32
#define HD 128
#define CMAX 4608
#define CLEN 4096
#define NCH 32          // 128-position chunks (4 waves x 32 pos, in-block combine)
#define SCALE 0.08838834764831845f   // 1/sqrt(128)

typedef _Float16 h2 __attribute__((ext_vector_type(2)));

__device__ __forceinline__ float4 ld4(const float* p) { return *reinterpret_cast<const float4*>(p); }
__device__ __forceinline__ float dot4(float4 a, float4 b) { return a.x*b.x + a.y*b.y + a.z*b.z + a.w*b.w; }

__device__ __forceinline__ h2 pk16(float x, float y) {
  return __builtin_bit_cast(h2, __builtin_amdgcn_cvt_pkrtz(x, y));
}

__device__ __forceinline__ float fdot2f(h2 a, h2 b, float c) {
#if __has_builtin(__builtin_amdgcn_fdot2)
  return __builtin_amdgcn_fdot2(a, b, c, false);
#else
  return c + (float)a.x * (float)b.x + (float)a.y * (float)b.y;
#endif
}

// ---------------------------------------------------------------------------
// GEMM (gemm3, proven): out[bs,o] = sum_k X[bs,k]*W[o,k], 4 waves/block,
// 2 outputs/wave, X double-buffered through LDS.
// ---------------------------------------------------------------------------
__global__ __launch_bounds__(256) void gemm3_kernel(
    const float* __restrict__ X,
    const float* __restrict__ W1, const float* __restrict__ W2, const float* __restrict__ W3,
    int n1, int n2,
    float* __restrict__ o1, int os1,
    float* __restrict__ o2, int os2,
    float* __restrict__ o3, int os3)
{
  __shared__ float Xs[2][16][256];

  const int tid = threadIdx.x, lane = tid & 63, w = tid >> 6;
  const int o = blockIdx.x * 8 + w * 2;

  const float* Wb; float* ob; int os;
  if (o < n1)           { Wb = W1 + (size_t)o * HIDK;            ob = o1 + o;            os = os1; }
  else if (o < n1 + n2) { const int f = o - n1;      Wb = W2 + (size_t)f * HIDK; ob = o2 + f; os = os2; }
  else                  { const int f = o - n1 - n2; Wb = W3 + (size_t)f * HIDK; ob = o3 + f; os = os3; }

  const int strow = tid >> 6;
  const int stcol = (tid & 63) * 4;

  float acc0[16], acc1[16];
  #pragma unroll
  for (int b = 0; b < 16; ++b) { acc0[b] = 0.f; acc1[b] = 0.f; }

  #pragma unroll
  for (int j = 0; j < 4; ++j)
    *(float4*)&Xs[0][strow + j * 4][stcol] = ld4(X + (size_t)(strow + j * 4) * HIDK + stcol);

  int cur = 0;
  #pragma unroll 2
  for (int kt = 0; kt < 16; ++kt) {
    const float4 w0 = ld4(Wb + (size_t)kt * 256 + lane * 4);
    const float4 w1 = ld4(Wb + HIDK + (size_t)kt * 256 + lane * 4);
    float4 g[4];
    if (kt < 15) {
      #pragma unroll
      for (int j = 0; j < 4; ++j)
        g[j] = ld4(X + (size_t)(strow + j * 4) * HIDK + (kt + 1) * 256 + stcol);
    }
    __syncthreads();
    #pragma unroll
    for (int b = 0; b < 16; ++b) {
      const float4 x4 = *(const float4*)&Xs[cur][b][lane * 4];
      acc0[b] += dot4(x4, w0);
      acc1[b] += dot4(x4, w1);
    }
    if (kt < 15) {
      #pragma unroll
      for (int j = 0; j < 4; ++j)
        *(float4*)&Xs[cur ^ 1][strow + j * 4][stcol] = g[j];
    }
    cur ^= 1;
  }

  #pragma unroll
  for (int m = 1; m < 64; m <<= 1)
    #pragma unroll
    for (int b = 0; b < 16; ++b) {
      acc0[b] += __shfl_xor(acc0[b], m, 64);
      acc1[b] += __shfl_xor(acc1[b], m, 64);
    }
  if (lane == 0) {
    #pragma unroll
    for (int b = 0; b < 16; ++b) {
      ob[(size_t)b * os]     = acc0[b];
      ob[(size_t)b * os + 1] = acc1[b];
    }
  }
}

// ---------------------------------------------------------------------------
// Q prep: RoPE * SCALE -> qt[bkv][r][d] (f32) and qth (fp16 copy)
// ---------------------------------------------------------------------------
__global__ __launch_bounds__(256) void qt_prep_kernel(
    const float* __restrict__ qraw, const float* __restrict__ cosp,
    const float* __restrict__ sinp, float* __restrict__ qt, __half* __restrict__ qth)
{
  const int e = blockIdx.x * 256 + threadIdx.x;   // 65536 total
  const int d = e & 127;
  const int r = (e >> 7) & 15;     // hl*4 + s
  const int bkv = e >> 11;         // 0..31
  const int b = bkv >> 3, kv = bkv & 7;
  const int s = r & 3, hl = r >> 2;
  const float* qp = qraw + (size_t)(b * 4 + s) * HIDK + (kv * 4 + hl) * HD;
  const float c  = cosp[(b * 4 + s) * HD + d];
  const float sn = sinp[(b * 4 + s) * HD + d];
  const float sgn = (d < 64) ? -1.f : 1.f;
  const float v = (qp[d] * c + sgn * qp[d ^ 64] * sn) * SCALE;
  qt[e] = v;
  qth[e] = (__half)v;
}

// ---------------------------------------------------------------------------
// Attention attn8: 1024 blocks (32 bkv x 32 chunks of 128 pos) x 256 thr
// (4 waves). Wave w owns 32 positions. Scores: lane=(pos,dh) fp16 fdot2,
// Q from LDS (fp16), K streamed per-lane + cvt_pk. Softmax per wave (one
// tile, no online). PV: lane=(d-quad, row-half), V coalesced-ish fp32.
// In-block 4-way flash combine -> NCH=32 fp16 partials. 2 barriers.
// NO launch_bounds min-waves (spill lesson R2/R10).
// ---------------------------------------------------------------------------
__global__ __launch_bounds__(256) void attn8_kernel(
    const __half* __restrict__ qth, const float* __restrict__ Kc, const float* __restrict__ Vc,
    __half* __restrict__ partOh, float* __restrict__ partM, float* __restrict__ partL)
{
  __shared__ __half qsh[16 * 128];        // 4 KB fp16 Q (RoPE'd*SCALE)
  __shared__ float  P[4][32][20];         // 10.25 KB per-wave probabilities
  __shared__ __half Oex[3 * 16 * 128];    // 12.3 KB waves 1-3 partial O
  __shared__ float  Mex[4][16];
  __shared__ float  Lex[4][16];

  const int tid = threadIdx.x, lane = tid & 63, w = tid >> 6;
  const int chunk = blockIdx.x & 31, bkv = blockIdx.x >> 5;
  const int b = bkv >> 3, kv = bkv & 7;
  const int p0 = chunk * 128;

  // ---- stage Q: 4KB in one b128 per thread ----
  ((float4*)qsh)[tid] = ((const float4*)(qth + (size_t)bkv * 2048))[tid];
  __syncthreads();

  // ---- scores: lane = (pos 0..31, d-half) ----
  const int pq = lane & 31, dh = lane >> 5;
  const int posg = p0 + w * 32 + pq;
  const float* Kp = Kc + ((size_t)bkv * CMAX + posg) * HD + dh * 64;

  float sc[16];
  #pragma unroll
  for (int r = 0; r < 16; ++r) sc[r] = 0.f;

  #pragma unroll
  for (int hf = 0; hf < 2; ++hf) {
    float4 kr[8];
    #pragma unroll
    for (int j = 0; j < 8; ++j) kr[j] = ld4(Kp + hf * 32 + j * 4);
    h2 kh[16];
    #pragma unroll
    for (int j = 0; j < 8; ++j) {
      kh[2 * j]     = pk16(kr[j].x, kr[j].y);
      kh[2 * j + 1] = pk16(kr[j].z, kr[j].w);
    }
    #pragma unroll
    for (int r = 0; r < 16; ++r) {
      const float4* qrow = (const float4*)&qsh[r * 128 + dh * 64 + hf * 32];
      float s = sc[r];
      #pragma unroll
      for (int g = 0; g < 4; ++g) {
        float4 q4 = qrow[g];
        h2 qh[4];
        __builtin_memcpy(qh, &q4, 16);
        s = fdot2f(kh[4 * g + 0], qh[0], s);
        s = fdot2f(kh[4 * g + 1], qh[1], s);
        s = fdot2f(kh[4 * g + 2], qh[2], s);
        s = fdot2f(kh[4 * g + 3], qh[3], s);
      }
      sc[r] = s;
    }
  }

  // ---- softmax over the wave's 32 positions ----
  float m[16], l[16];
  #pragma unroll
  for (int r = 0; r < 16; ++r) {
    sc[r] += __shfl_xor(sc[r], 32, 64);      // combine d-halves
    float mx = sc[r];
    #pragma unroll
    for (int st = 1; st < 32; st <<= 1) mx = fmaxf(mx, __shfl_xor(mx, st, 64));
    const float p = __expf(sc[r] - mx);
    float ls = p;
    #pragma unroll
    for (int st = 1; st < 32; st <<= 1) ls += __shfl_xor(ls, st, 64);
    m[r] = mx; l[r] = ls;
    if (dh == 0) P[w][pq][r] = p;
  }
  // (wave-private P: no barrier needed before same-wave PV reads)

  // ---- PV: lane = (d-quad dc, row-half rh) ----
  const int dc = lane & 31, rh = lane >> 5;
  const float* Vp = Vc + ((size_t)bkv * CMAX + p0 + w * 32) * HD + dc * 4;

  float4 o[8];
  #pragma unroll
  for (int j = 0; j < 8; ++j) o[j] = make_float4(0.f, 0.f, 0.f, 0.f);

  float4 vb[4];
  #pragma unroll
  for (int j = 0; j < 4; ++j) vb[j] = ld4(Vp + (size_t)j * HD);

  #pragma unroll
  for (int i = 0; i < 32; ++i) {
    const float4 v4 = vb[i & 3];
    if (i < 28) vb[i & 3] = ld4(Vp + (size_t)(i + 4) * HD);
    const float4 pa = *(const float4*)&P[w][i][rh * 8];
    const float4 pb = *(const float4*)&P[w][i][rh * 8 + 4];
    o[0].x += pa.x * v4.x; o[0].y += pa.x * v4.y; o[0].z += pa.x * v4.z; o[0].w += pa.x * v4.w;
    o[1].x += pa.y * v4.x; o[1].y += pa.y * v4.y; o[1].z += pa.y * v4.z; o[1].w += pa.y * v4.w;
    o[2].x += pa.z * v4.x; o[2].y += pa.z * v4.y; o[2].z += pa.z * v4.z; o[2].w += pa.z * v4.w;
    o[3].x += pa.w * v4.x; o[3].y += pa.w * v4.y; o[3].z += pa.w * v4.z; o[3].w += pa.w * v4.w;
    o[4].x += pb.x * v4.x; o[4].y += pb.x * v4.y; o[4].z += pb.x * v4.z; o[4].w += pb.x * v4.w;
    o[5].x += pb.y * v4.x; o[5].y += pb.y * v4.y; o[5].z += pb.y * v4.z; o[5].w += pb.y * v4.w;
    o[6].x += pb.z * v4.x; o[6].y += pb.z * v4.y; o[6].z += pb.z * v4.z; o[6].w += pb.z * v4.w;
    o[7].x += pb.w * v4.x; o[7].y += pb.w * v4.y; o[7].z += pb.w * v4.z; o[7].w += pb.w * v4.w;
  }

  // ---- in-block 4-way flash combine ----
  if (lane == 0) {
    #pragma unroll
    for (int r = 0; r < 16; ++r) { Mex[w][r] = m[r]; Lex[w][r] = l[r]; }
  }
  if (w > 0) {
    #pragma unroll
    for (int j = 0; j < 8; ++j) {
      const int row = rh * 8 + j;
      __half2* dst = (__half2*)&Oex[((w - 1) * 16 + row) * 128 + dc * 4];
      dst[0] = __floats2half2_rn(o[j].x, o[j].y);
      dst[1] = __floats2half2_rn(o[j].z, o[j].w);
    }
  }
  __syncthreads();
  if (w == 0) {
    #pragma unroll
    for (int j = 0; j < 8; ++j) {
      const int row = rh * 8 + j;
      const float m0 = Mex[0][row], m1 = Mex[1][row], m2 = Mex[2][row], m3 = Mex[3][row];
      const float M = fmaxf(fmaxf(m0, m1), fmaxf(m2, m3));
      const float a0 = __expf(m0 - M), a1 = __expf(m1 - M);
      const float a2 = __expf(m2 - M), a3 = __expf(m3 - M);
      float4 O;
      O.x = a0 * o[j].x; O.y = a0 * o[j].y; O.z = a0 * o[j].z; O.w = a0 * o[j].w;
      {
        const __half2* s1 = (const __half2*)&Oex[(0 * 16 + row) * 128 + dc * 4];
        const float2 x0 = __half22float2(s1[0]), x1 = __half22float2(s1[1]);
        O.x += a1 * x0.x; O.y += a1 * x0.y; O.z += a1 * x1.x; O.w += a1 * x1.y;
      }
      {
        const __half2* s2 = (const __half2*)&Oex[(1 * 16 + row) * 128 + dc * 4];
        const float2 x0 = __half22float2(s2[0]), x1 = __half22float2(s2[1]);
        O.x += a2 * x0.x; O.y += a2 * x0.y; O.z += a2 * x1.x; O.w += a2 * x1.y;
      }
      {
        const __half2* s3 = (const __half2*)&Oex[(2 * 16 + row) * 128 + dc * 4];
        const float2 x0 = __half22float2(s3[0]), x1 = __half22float2(s3[1]);
        O.x += a3 * x0.x; O.y += a3 * x0.y; O.z += a3 * x1.x; O.w += a3 * x1.y;
      }
      const float lf = a0 * Lex[0][row] + a1 * Lex[1][row] + a2 * Lex[2][row] + a3 * Lex[3][row];
      const int hl = row >> 2, s = row & 3;
      const int grow = (b * NHQ + kv * 4 + hl) * 4 + s;
      const size_t idx = ((size_t)grow * NCH + chunk) * HD + dc * 4;
      *(__half2*)&partOh[idx]     = __floats2half2_rn(O.x, O.y);
      *(__half2*)&partOh[idx + 2] = __floats2half2_rn(O.z, O.w);
      if (dc == 0) {
        partM[grow * NCH + chunk] = M;
        partL[grow * NCH + chunk] = lf;
      }
    }
  }
}

// ---------------------------------------------------------------------------
// Flash-combine 32 chunk partials (fp16) + <=4 new causal tokens. 512 x 64.
// ---------------------------------------------------------------------------
__global__ __launch_bounds__(64) void combine_kernel(
    const float* __restrict__ qt, const float* __restrict__ kraw, const float* __restrict__ vraw,
    const float* __restrict__ cosp, const float* __restrict__ sinp,
    const __half* __restrict__ partOh, const float* __restrict__ partM, const float* __restrict__ partL,
    float* __restrict__ attn)
{
  const int bid = blockIdx.x;             // ((b*32 + h)*4 + s)
  const int s = bid & 3;
  const int h = (bid >> 2) & 31;
  const int b = bid >> 7;
  const int kv = h >> 2;
  const int lane = threadIdx.x;
  const int d0 = lane * 2;

  float M = -INFINITY;
  #pragma unroll 4
  for (int c = 0; c < NCH; ++c) M = fmaxf(M, partM[bid * NCH + c]);

  const int rloc = (h & 3) * 4 + s;
  const float qr0 = qt[((size_t)(b * 8 + kv) * 16 + rloc) * 128 + d0];
  const float qr1 = qt[((size_t)(b * 8 + kv) * 16 + rloc) * 128 + d0 + 1];

  float sj[4] = {0.f, 0.f, 0.f, 0.f};
  float Mp = M;
  #pragma unroll
  for (int j = 0; j < 4; ++j) {
    if (j <= s) {
      const float* kp = kraw + (size_t)(b * 4 + j) * 1024 + kv * HD;
      const float c0 = cosp[(b * 4 + j) * HD + d0],     sn0 = sinp[(b * 4 + j) * HD + d0];
      const float c1 = cosp[(b * 4 + j) * HD + d0 + 1], sn1 = sinp[(b * 4 + j) * HD + d0 + 1];
      const float sg0 = (d0 < 64) ? -1.f : 1.f;
      const float sg1 = ((d0 + 1) < 64) ? -1.f : 1.f;
      const float kr0 = kp[d0] * c0 + sg0 * kp[d0 ^ 64] * sn0;
      const float kr1 = kp[d0 + 1] * c1 + sg1 * kp[(d0 + 1) ^ 64] * sn1;
      float part = qr0 * kr0 + qr1 * kr1;
      #pragma unroll
      for (int m = 1; m < 64; m <<= 1) part += __shfl_xor(part, m, 64);
      sj[j] = part;
      Mp = fmaxf(Mp, part);
    }
  }

  float ltot = 0.f, O0 = 0.f, O1 = 0.f;
  #pragma unroll 4
  for (int c = 0; c < NCH; ++c) {
    const float a = __expf(partM[bid * NCH + c] - Mp);
    ltot += partL[bid * NCH + c] * a;
    const float2 v = __half22float2(*(const __half2*)&partOh[((size_t)bid * NCH + c) * HD + d0]);
    O0 += a * v.x;
    O1 += a * v.y;
  }
  #pragma unroll
  for (int j = 0; j < 4; ++j) {
    if (j <= s) {
      const float e = __expf(sj[j] - Mp);
      ltot += e;
      const float* vp = vraw + (size_t)(b * 4 + j) * 1024 + kv * HD + d0;
      O0 += e * vp[0];
      O1 += e * vp[1];
    }
  }
  const float inv = 1.f / ltot;
  *(float2*)&attn[(size_t)(b * 4 + s) * HIDK + h * HD + d0] = make_float2(O0 * inv, O1 * inv);
}

// ---------------------------------------------------------------------------
extern "C" void kernel_launch(void* const* d_in, const int* in_sizes, int n_in,
                              void* d_out, int out_size, void* d_ws, size_t ws_size,
                              hipStream_t stream)
{
  const float* hid  = (const float*)d_in[0];
  const float* cosp = (const float*)d_in[1];
  const float* sinp = (const float*)d_in[2];
  const float* Kc   = (const float*)d_in[3];
  const float* Vc   = (const float*)d_in[4];
  const float* Wq   = (const float*)d_in[5];
  const float* Wk   = (const float*)d_in[6];
  const float* Wv   = (const float*)d_in[7];
  const float* Wo   = (const float*)d_in[8];
  float* out = (float*)d_out;

  float* ws    = (float*)d_ws;
  float*  kraw   = ws;                      // 16384
  float*  vraw   = ws + 16384;              // 16384
  float*  attn   = ws + 32768;              // 65536
  float*  qt     = ws + 98304;              // 65536
  __half* qth    = (__half*)(ws + 163840);  // 65536 halves = 32768 float-slots
  float*  qraw   = ws + 196608;             // 65536
  float*  partM  = ws + 262144;             // 512*32 = 16384
  float*  partL  = ws + 278528;             // 16384
  __half* partOh = (__half*)(ws + 294912);  // 512*32*128 halves = 1048576 float-slots
  // total 1,343,488 floats = 5.37 MB

  // A: QKV projection (raw, un-roped)
  gemm3_kernel<<<768, 256, 0, stream>>>(hid, Wq, Wk, Wv, 4096, 1024,
                                        qraw, 4096, kraw, 1024, vraw, 1024);
  // A': RoPE + scale q -> qt (f32) + qth (fp16)
  qt_prep_kernel<<<256, 256, 0, stream>>>(qraw, cosp, sinp, qt, qth);
  // B: attention over the 4096 cached positions
  attn8_kernel<<<1024, 256, 0, stream>>>(qth, Kc, Vc, partOh, partM, partL);
  // C: combine + new causal tokens
  combine_kernel<<<512, 64, 0, stream>>>(qt, kraw, vraw, cosp, sinp,
                                         partOh, partM, partL, attn);
  // D: output projection
  gemm3_kernel<<<512, 256, 0, stream>>>(attn, Wo, Wo, Wo, 4096, 0,
                                        out, 4096, out, 4096, out, 4096);
}

// Round 13
// 154.376 us; speedup vs baseline: 1.7887x; 1.0358x over previous
//
#include <hip/hip_runtime.h>
#include <hip/hip_fp16.h>
#include <math.h>

#define HIDK 4096
#define NHQ 32
#define HD 128
#define CMAX 4608
#define CLEN 4096
#define NCH 16          // 256-position chunks (4 waves x 64 pos, in-block combine)
#define SCALE 0.08838834764831845f   // 1/sqrt(128)

__device__ __forceinline__ float4 ld4(const float* p) { return *reinterpret_cast<const float4*>(p); }
__device__ __forceinline__ float dot4(float4 a, float4 b) { return a.x*b.x + a.y*b.y + a.z*b.z + a.w*b.w; }

// ---------------------------------------------------------------------------
// GEMM (gemm3, proven): out[bs,o] = sum_k X[bs,k]*W[o,k], 4 waves/block,
// 2 outputs/wave, X double-buffered through LDS.
// ---------------------------------------------------------------------------
__global__ __launch_bounds__(256) void gemm3_kernel(
    const float* __restrict__ X,
    const float* __restrict__ W1, const float* __restrict__ W2, const float* __restrict__ W3,
    int n1, int n2,
    float* __restrict__ o1, int os1,
    float* __restrict__ o2, int os2,
    float* __restrict__ o3, int os3)
{
  __shared__ float Xs[2][16][256];

  const int tid = threadIdx.x, lane = tid & 63, w = tid >> 6;
  const int o = blockIdx.x * 8 + w * 2;

  const float* Wb; float* ob; int os;
  if (o < n1)           { Wb = W1 + (size_t)o * HIDK;            ob = o1 + o;            os = os1; }
  else if (o < n1 + n2) { const int f = o - n1;      Wb = W2 + (size_t)f * HIDK; ob = o2 + f; os = os2; }
  else                  { const int f = o - n1 - n2; Wb = W3 + (size_t)f * HIDK; ob = o3 + f; os = os3; }

  const int strow = tid >> 6;
  const int stcol = (tid & 63) * 4;

  float acc0[16], acc1[16];
  #pragma unroll
  for (int b = 0; b < 16; ++b) { acc0[b] = 0.f; acc1[b] = 0.f; }

  #pragma unroll
  for (int j = 0; j < 4; ++j)
    *(float4*)&Xs[0][strow + j * 4][stcol] = ld4(X + (size_t)(strow + j * 4) * HIDK + stcol);

  int cur = 0;
  #pragma unroll 2
  for (int kt = 0; kt < 16; ++kt) {
    const float4 w0 = ld4(Wb + (size_t)kt * 256 + lane * 4);
    const float4 w1 = ld4(Wb + HIDK + (size_t)kt * 256 + lane * 4);
    float4 g[4];
    if (kt < 15) {
      #pragma unroll
      for (int j = 0; j < 4; ++j)
        g[j] = ld4(X + (size_t)(strow + j * 4) * HIDK + (kt + 1) * 256 + stcol);
    }
    __syncthreads();
    #pragma unroll
    for (int b = 0; b < 16; ++b) {
      const float4 x4 = *(const float4*)&Xs[cur][b][lane * 4];
      acc0[b] += dot4(x4, w0);
      acc1[b] += dot4(x4, w1);
    }
    if (kt < 15) {
      #pragma unroll
      for (int j = 0; j < 4; ++j)
        *(float4*)&Xs[cur ^ 1][strow + j * 4][stcol] = g[j];
    }
    cur ^= 1;
  }

  #pragma unroll
  for (int m = 1; m < 64; m <<= 1)
    #pragma unroll
    for (int b = 0; b < 16; ++b) {
      acc0[b] += __shfl_xor(acc0[b], m, 64);
      acc1[b] += __shfl_xor(acc1[b], m, 64);
    }
  if (lane == 0) {
    #pragma unroll
    for (int b = 0; b < 16; ++b) {
      ob[(size_t)b * os]     = acc0[b];
      ob[(size_t)b * os + 1] = acc1[b];
    }
  }
}

// ---------------------------------------------------------------------------
// Q prep: RoPE * SCALE -> qt[bkv][r][d]  (r = hl*4+s, d = 0..127)
// ---------------------------------------------------------------------------
__global__ __launch_bounds__(256) void qt_prep_kernel(
    const float* __restrict__ qraw, const float* __restrict__ cosp,
    const float* __restrict__ sinp, float* __restrict__ qt)
{
  const int e = blockIdx.x * 256 + threadIdx.x;   // 65536 total
  const int d = e & 127;
  const int r = (e >> 7) & 15;     // hl*4 + s
  const int bkv = e >> 11;         // 0..31
  const int b = bkv >> 3, kv = bkv & 7;
  const int s = r & 3, hl = r >> 2;
  const float* qp = qraw + (size_t)(b * 4 + s) * HIDK + (kv * 4 + hl) * HD;
  const float c  = cosp[(b * 4 + s) * HD + d];
  const float sn = sinp[(b * 4 + s) * HD + d];
  const float sgn = (d < 64) ? -1.f : 1.f;
  qt[e] = (qp[d] * c + sgn * qp[d ^ 64] * sn) * SCALE;
}

// ---------------------------------------------------------------------------
// Attention attn9: 512 blocks (32 bkv x 16 chunks of 256 pos) x 256 thr
// (4 waves, each owns 64 positions). 4096 waves = 16/CU.
// Scores: lane = position, Q via WAVE-UNIFORM global reads (no lane term in
// the index -> scalar/broadcast path, no LDS, no shuffles in the dot).
// K streamed per-lane with 4-deep static ring. Softmax = one butterfly.
// PV: lane=(d-quad, row-half), V coalesced, P broadcast b128 from LDS.
// In-block 4-way flash combine -> NCH=16 fp16 partials. fp32 math.
// NO launch_bounds min-waves; register budget kept ~100.
// ---------------------------------------------------------------------------
__global__ __launch_bounds__(256) void attn9_kernel(
    const float* __restrict__ qt, const float* __restrict__ Kc, const float* __restrict__ Vc,
    __half* __restrict__ partOh, float* __restrict__ partM, float* __restrict__ partL)
{
  __shared__ float  P[4][64][20];         // 20.5 KB per-wave probabilities [pos][row]
  __shared__ __half Oex[3 * 16 * 128];    // 12.3 KB waves 1-3 partial O
  __shared__ float  Mex[4][16];
  __shared__ float  Lex[4][16];

  const int tid = threadIdx.x, lane = tid & 63, w = tid >> 6;
  const int chunk = blockIdx.x & 15, bkv = blockIdx.x >> 4;
  const int b = bkv >> 3, kv = bkv & 7;
  const int p0 = chunk * 256;

  const float* qb = qt + (size_t)bkv * 2048;    // block-uniform Q [r][128]

  // ---- scores: lane = position (64 per wave) ----
  const int posg = p0 + w * 64 + lane;
  const float* Kp = Kc + ((size_t)bkv * CMAX + posg) * HD;

  float sc[16];
  #pragma unroll
  for (int r = 0; r < 16; ++r) sc[r] = 0.f;

  {
    float4 kb[4];
    #pragma unroll
    for (int j = 0; j < 4; ++j) kb[j] = ld4(Kp + j * 4);

    #pragma unroll 4
    for (int i = 0; i < 32; ++i) {
      const float4 k4 = kb[i & 3];
      if (i < 28) kb[i & 3] = ld4(Kp + (i + 4) * 4);
      #pragma unroll
      for (int r = 0; r < 16; ++r) {
        const float4 q4 = ld4(qb + r * 128 + i * 4);   // uniform address
        sc[r] += dot4(k4, q4);
      }
    }
  }

  // ---- softmax over the wave's 64 positions (butterfly) ----
  #pragma unroll
  for (int r = 0; r < 16; ++r) {
    float mx = sc[r];
    #pragma unroll
    for (int st = 1; st < 64; st <<= 1) mx = fmaxf(mx, __shfl_xor(mx, st, 64));
    const float p = __expf(sc[r] - mx);
    float ls = p;
    #pragma unroll
    for (int st = 1; st < 64; st <<= 1) ls += __shfl_xor(ls, st, 64);
    P[w][lane][r] = p;
    if (lane == 0) { Mex[w][r] = mx; Lex[w][r] = ls; }
  }
  // wave-private P: same-wave PV reads need no barrier

  // ---- PV: lane = (d-quad dc, row-half rh), V coalesced ----
  const int dc = lane & 31, rh = lane >> 5;
  const float* Vp = Vc + ((size_t)bkv * CMAX + p0 + w * 64) * HD + dc * 4;

  float4 o[8];
  #pragma unroll
  for (int j = 0; j < 8; ++j) o[j] = make_float4(0.f, 0.f, 0.f, 0.f);

  {
    float4 vb[4];
    #pragma unroll
    for (int j = 0; j < 4; ++j) vb[j] = ld4(Vp + (size_t)j * HD);

    #pragma unroll 4
    for (int i = 0; i < 64; ++i) {
      const float4 v4 = vb[i & 3];
      if (i < 60) vb[i & 3] = ld4(Vp + (size_t)(i + 4) * HD);
      const float4 pa = *(const float4*)&P[w][i][rh * 8];
      const float4 pb = *(const float4*)&P[w][i][rh * 8 + 4];
      o[0].x += pa.x * v4.x; o[0].y += pa.x * v4.y; o[0].z += pa.x * v4.z; o[0].w += pa.x * v4.w;
      o[1].x += pa.y * v4.x; o[1].y += pa.y * v4.y; o[1].z += pa.y * v4.z; o[1].w += pa.y * v4.w;
      o[2].x += pa.z * v4.x; o[2].y += pa.z * v4.y; o[2].z += pa.z * v4.z; o[2].w += pa.z * v4.w;
      o[3].x += pa.w * v4.x; o[3].y += pa.w * v4.y; o[3].z += pa.w * v4.z; o[3].w += pa.w * v4.w;
      o[4].x += pb.x * v4.x; o[4].y += pb.x * v4.y; o[4].z += pb.x * v4.z; o[4].w += pb.x * v4.w;
      o[5].x += pb.y * v4.x; o[5].y += pb.y * v4.y; o[5].z += pb.y * v4.z; o[5].w += pb.y * v4.w;
      o[6].x += pb.z * v4.x; o[6].y += pb.z * v4.y; o[6].z += pb.z * v4.z; o[6].w += pb.z * v4.w;
      o[7].x += pb.w * v4.x; o[7].y += pb.w * v4.y; o[7].z += pb.w * v4.z; o[7].w += pb.w * v4.w;
    }
  }

  // ---- in-block 4-way flash combine (pattern validated in R12) ----
  if (w > 0) {
    #pragma unroll
    for (int j = 0; j < 8; ++j) {
      const int row = rh * 8 + j;
      __half2* dst = (__half2*)&Oex[((w - 1) * 16 + row) * 128 + dc * 4];
      dst[0] = __floats2half2_rn(o[j].x, o[j].y);
      dst[1] = __floats2half2_rn(o[j].z, o[j].w);
    }
  }
  __syncthreads();
  if (w == 0) {
    #pragma unroll
    for (int j = 0; j < 8; ++j) {
      const int row = rh * 8 + j;
      const float m0 = Mex[0][row], m1 = Mex[1][row], m2 = Mex[2][row], m3 = Mex[3][row];
      const float M = fmaxf(fmaxf(m0, m1), fmaxf(m2, m3));
      const float a0 = __expf(m0 - M), a1 = __expf(m1 - M);
      const float a2 = __expf(m2 - M), a3 = __expf(m3 - M);
      float4 O;
      O.x = a0 * o[j].x; O.y = a0 * o[j].y; O.z = a0 * o[j].z; O.w = a0 * o[j].w;
      {
        const __half2* s1 = (const __half2*)&Oex[(0 * 16 + row) * 128 + dc * 4];
        const float2 x0 = __half22float2(s1[0]), x1 = __half22float2(s1[1]);
        O.x += a1 * x0.x; O.y += a1 * x0.y; O.z += a1 * x1.x; O.w += a1 * x1.y;
      }
      {
        const __half2* s2 = (const __half2*)&Oex[(1 * 16 + row) * 128 + dc * 4];
        const float2 x0 = __half22float2(s2[0]), x1 = __half22float2(s2[1]);
        O.x += a2 * x0.x; O.y += a2 * x0.y; O.z += a2 * x1.x; O.w += a2 * x1.y;
      }
      {
        const __half2* s3 = (const __half2*)&Oex[(2 * 16 + row) * 128 + dc * 4];
        const float2 x0 = __half22float2(s3[0]), x1 = __half22float2(s3[1]);
        O.x += a3 * x0.x; O.y += a3 * x0.y; O.z += a3 * x1.x; O.w += a3 * x1.y;
      }
      const float lf = a0 * Lex[0][row] + a1 * Lex[1][row] + a2 * Lex[2][row] + a3 * Lex[3][row];
      const int hl = row >> 2, s = row & 3;
      const int grow = (b * NHQ + kv * 4 + hl) * 4 + s;
      const size_t idx = ((size_t)grow * NCH + chunk) * HD + dc * 4;
      *(__half2*)&partOh[idx]     = __floats2half2_rn(O.x, O.y);
      *(__half2*)&partOh[idx + 2] = __floats2half2_rn(O.z, O.w);
      if (dc == 0) {
        partM[grow * NCH + chunk] = M;
        partL[grow * NCH + chunk] = lf;
      }
    }
  }
}

// ---------------------------------------------------------------------------
// Flash-combine 16 chunk partials (fp16) + <=4 new causal tokens. 512 x 64.
// ---------------------------------------------------------------------------
__global__ __launch_bounds__(64) void combine_kernel(
    const float* __restrict__ qt, const float* __restrict__ kraw, const float* __restrict__ vraw,
    const float* __restrict__ cosp, const float* __restrict__ sinp,
    const __half* __restrict__ partOh, const float* __restrict__ partM, const float* __restrict__ partL,
    float* __restrict__ attn)
{
  const int bid = blockIdx.x;             // ((b*32 + h)*4 + s)
  const int s = bid & 3;
  const int h = (bid >> 2) & 31;
  const int b = bid >> 7;
  const int kv = h >> 2;
  const int lane = threadIdx.x;
  const int d0 = lane * 2;

  float M = -INFINITY;
  #pragma unroll 4
  for (int c = 0; c < NCH; ++c) M = fmaxf(M, partM[bid * NCH + c]);

  const int rloc = (h & 3) * 4 + s;
  const float qr0 = qt[((size_t)(b * 8 + kv) * 16 + rloc) * 128 + d0];
  const float qr1 = qt[((size_t)(b * 8 + kv) * 16 + rloc) * 128 + d0 + 1];

  float sj[4] = {0.f, 0.f, 0.f, 0.f};
  float Mp = M;
  #pragma unroll
  for (int j = 0; j < 4; ++j) {
    if (j <= s) {
      const float* kp = kraw + (size_t)(b * 4 + j) * 1024 + kv * HD;
      const float c0 = cosp[(b * 4 + j) * HD + d0],     sn0 = sinp[(b * 4 + j) * HD + d0];
      const float c1 = cosp[(b * 4 + j) * HD + d0 + 1], sn1 = sinp[(b * 4 + j) * HD + d0 + 1];
      const float sg0 = (d0 < 64) ? -1.f : 1.f;
      const float sg1 = ((d0 + 1) < 64) ? -1.f : 1.f;
      const float kr0 = kp[d0] * c0 + sg0 * kp[d0 ^ 64] * sn0;
      const float kr1 = kp[d0 + 1] * c1 + sg1 * kp[(d0 + 1) ^ 64] * sn1;
      float part = qr0 * kr0 + qr1 * kr1;
      #pragma unroll
      for (int m = 1; m < 64; m <<= 1) part += __shfl_xor(part, m, 64);
      sj[j] = part;
      Mp = fmaxf(Mp, part);
    }
  }

  float ltot = 0.f, O0 = 0.f, O1 = 0.f;
  #pragma unroll 4
  for (int c = 0; c < NCH; ++c) {
    const float a = __expf(partM[bid * NCH + c] - Mp);
    ltot += partL[bid * NCH + c] * a;
    const float2 v = __half22float2(*(const __half2*)&partOh[((size_t)bid * NCH + c) * HD + d0]);
    O0 += a * v.x;
    O1 += a * v.y;
  }
  #pragma unroll
  for (int j = 0; j < 4; ++j) {
    if (j <= s) {
      const float e = __expf(sj[j] - Mp);
      ltot += e;
      const float* vp = vraw + (size_t)(b * 4 + j) * 1024 + kv * HD + d0;
      O0 += e * vp[0];
      O1 += e * vp[1];
    }
  }
  const float inv = 1.f / ltot;
  *(float2*)&attn[(size_t)(b * 4 + s) * HIDK + h * HD + d0] = make_float2(O0 * inv, O1 * inv);
}

// ---------------------------------------------------------------------------
extern "C" void kernel_launch(void* const* d_in, const int* in_sizes, int n_in,
                              void* d_out, int out_size, void* d_ws, size_t ws_size,
                              hipStream_t stream)
{
  const float* hid  = (const float*)d_in[0];
  const float* cosp = (const float*)d_in[1];
  const float* sinp = (const float*)d_in[2];
  const float* Kc   = (const float*)d_in[3];
  const float* Vc   = (const float*)d_in[4];
  const float* Wq   = (const float*)d_in[5];
  const float* Wk   = (const float*)d_in[6];
  const float* Wv   = (const float*)d_in[7];
  const float* Wo   = (const float*)d_in[8];
  float* out = (float*)d_out;

  float* ws    = (float*)d_ws;
  float*  kraw   = ws;                      // 16384
  float*  vraw   = ws + 16384;              // 16384
  float*  attn   = ws + 32768;              // 65536
  float*  qt     = ws + 98304;              // 65536
  float*  qraw   = ws + 163840;             // 65536
  float*  partM  = ws + 229376;             // 512*16 = 8192
  float*  partL  = ws + 237568;             // 8192
  __half* partOh = (__half*)(ws + 245760);  // 512*16*128 halves = 524288 float-slots
  // total 770,048 floats = 3.08 MB (well under proven)

  // A: QKV projection (raw, un-roped)
  gemm3_kernel<<<768, 256, 0, stream>>>(hid, Wq, Wk, Wv, 4096, 1024,
                                        qraw, 4096, kraw, 1024, vraw, 1024);
  // A': RoPE + scale q -> qt[bkv][r][d]
  qt_prep_kernel<<<256, 256, 0, stream>>>(qraw, cosp, sinp, qt);
  // B: attention over the 4096 cached positions
  attn9_kernel<<<512, 256, 0, stream>>>(qt, Kc, Vc, partOh, partM, partL);
  // C: combine + new causal tokens
  combine_kernel<<<512, 64, 0, stream>>>(qt, kraw, vraw, cosp, sinp,
                                         partOh, partM, partL, attn);
  // D: output projection
  gemm3_kernel<<<512, 256, 0, stream>>>(attn, Wo, Wo, Wo, 4096, 0,
                                        out, 4096, out, 4096, out, 4096);
}